// Round 3
// baseline (635.047 us; speedup 1.0000x reference)
//
#include <hip/hip_runtime.h>

// Problem constants (fixed by reference)
#define CC 32
#define HH 256
#define WW 512
#define NN 4
#define MAXD 48

// Tiling: 256-wide w chunk, r-only LDS staged in TWO 16-channel halves,
// 256-thread blocks (4 waves), per-thread 4w x 12d register tile.
// Staging is SYNCHRONOUS (float4 load + ds_write) — the proven round-0 path.
// (Resubmission of round-1 source: round-1/2 failures diagnosed as infra
// acquisition flakes, not kernel-caused — see session journal.)
#define WT 256
#define RW (WT + MAXD)    // 304 r columns staged (w0-48 .. w0+255)
#define CH 16             // channels per staging pass (2 passes)
#define DTILE 12          // d per thread; d0 = 12*dg (mult of 4 -> aligned window)
#define WTILE 4           // w per thread; wb mult of 4 -> aligned float4
// block = 256 threads = 64 w-groups x 4 d-groups (dg wave-uniform: dg = t>>6)
// LDS = 16*304*4 = 19456 B -> 8 blocks/CU; VGPR<=64 (launch_bounds 256,8)
// -> 32 waves/CU (100% occupancy); grid 2048 = exactly 8 blocks x 256 CU.

__global__ __launch_bounds__(256, 8)
void cost_volume_kernel(const float* __restrict__ L,
                        const float* __restrict__ R,
                        float* __restrict__ out)
{
    __shared__ float r_s[CH][RW];        // 19 KB, r only; l stays in global/regs

    const int t  = threadIdx.x;          // 0..255
    const int w0 = blockIdx.x * WT;      // 0 or 256
    const int h  = blockIdx.y;
    const int n  = blockIdx.z;

    const size_t chw  = (size_t)HH * WW;                       // channel stride
    const size_t rowB = (size_t)n * CC * chw + (size_t)h * WW; // (n, c=0, h, 0)

    const int wg = t & 63;               // dg wave-uniform
    const int dg = t >> 6;               // 0..3
    const int wb = wg * WTILE;           // 0..252, multiple of 4
    const int d0 = dg * DTILE;           // 0,12,24,36
    // r_s col for (local w, d) is lw + 48 - d; needed [wb+37-d0, wb+51-d0];
    // aligned 16-float superset starts at:
    const int jA = wb + 36 - d0;         // multiple of 4; 0..288, +15 <= 303

    float acc[DTILE][WTILE];
    #pragma unroll
    for (int k = 0; k < DTILE; ++k)
        #pragma unroll
        for (int i = 0; i < WTILE; ++i)
            acc[k][i] = 0.f;

    // L prefetch chain (2-deep), runs straight through both halves
    const float* lp = L + rowB + w0 + wb;     // + c*chw per channel, aligned
    float4 lv0 = *(const float4*)(lp);
    float4 lv1 = *(const float4*)(lp + chw);

    for (int half = 0; half < 2; ++half) {
        const int c0 = half * CH;
        if (half) __syncthreads();       // drain half-0 compute before restage

        // ---- stage r: 16 rows x 76 float4 = 1216 slots, ~4.75/thread, coalesced
        #pragma unroll
        for (int k = 0; k < 5; ++k) {
            int idx = t + 256 * k;       // 0..1279
            if (idx < CH * 76) {
                int c   = idx / 76;      // 76 float4 per row
                int j4  = idx - c * 76;
                int g   = w0 - MAXD + 4 * j4;    // global w of this float4
                float4 v = make_float4(0.f, 0.f, 0.f, 0.f);
                if (g >= 0)              // w<0 -> zeros (zero pad / w<d)
                    v = *(const float4*)(R + rowB + (size_t)(c0 + c) * chw + g);
                *(float4*)&r_s[c][4 * j4] = v;
            }
        }
        __syncthreads();

        for (int cc = 0; cc < CH; ++cc) {
            const int c = c0 + cc;
            float4 lnext;
            if (c + 2 < CC)                       // uniform branch
                lnext = *(const float4*)(lp + (size_t)(c + 2) * chw);
            float rv[16];
            #pragma unroll
            for (int q = 0; q < 4; ++q)
                *(float4*)&rv[4 * q] = *(const float4*)&r_s[cc][jA + 4 * q];
            const float lf[4] = {lv0.x, lv0.y, lv0.z, lv0.w};
            #pragma unroll
            for (int k = 0; k < DTILE; ++k)
                #pragma unroll
                for (int i = 0; i < WTILE; ++i)
                    acc[k][i] += lf[i] * rv[12 + i - k];   // offsets 1..15, compile-time
            lv0 = lv1;
            lv1 = lnext;
        }
    }

    const float inv = 1.0f / 32.0f;      // mean over C, exact pow2
    #pragma unroll
    for (int k = 0; k < DTILE; ++k) {
        const int d = d0 + k;
        float4 o = make_float4(acc[k][0] * inv, acc[k][1] * inv,
                               acc[k][2] * inv, acc[k][3] * inv);
        *(float4*)(out + (((size_t)n * MAXD + d) * HH + h) * WW + w0 + wb) = o;
    }
}

extern "C" void kernel_launch(void* const* d_in, const int* in_sizes, int n_in,
                              void* d_out, int out_size, void* d_ws, size_t ws_size,
                              hipStream_t stream) {
    const float* L = (const float*)d_in[0];
    const float* R = (const float*)d_in[1];
    float* out = (float*)d_out;
    // d_in[2] (use_naive) is ignored per reference.
    dim3 grid(WW / WT, HH, NN);          // 2 x 256 x 4 = 2048 blocks
    cost_volume_kernel<<<grid, dim3(256, 1, 1), 0, stream>>>(L, R, out);
}

// Round 4
// 452.054 us; speedup vs baseline: 1.4048x; 1.4048x over previous
//
#include <hip/hip_runtime.h>

// Problem constants (fixed by reference)
#define CC 32
#define HH 256
#define WW 512
#define NN 4
#define MAXD 48

// Tiling: 256-wide w chunk, r-only LDS staged in TWO 16-channel halves,
// 256-thread blocks (4 waves), per-thread 4w x 12d register tile.
// LDS = 16*304*4 = 19456 B -> LDS permits 8 blocks/CU (vs 4 at round-0's 38 KB).
// __launch_bounds__(256,4): round-3 showed (256,8) forces VGPR=32 + acc spill
// (FETCH 72->558 MB, WRITE 106->1187 MB, dur 95->507 us). With (256,4) this
// structure compiles to 64 VGPR (round-0 evidence) and 64 VGPR already allows
// 8 waves/SIMD in hardware -> 8 blocks/CU without squeezing the allocator.
#define WT 256
#define RW (WT + MAXD)    // 304 r columns staged (w0-48 .. w0+255)
#define CH 16             // channels per staging pass (2 passes)
#define DTILE 12          // d per thread; d0 = 12*dg (mult of 4 -> aligned window)
#define WTILE 4           // w per thread; wb mult of 4 -> aligned float4

__global__ __launch_bounds__(256, 4)
void cost_volume_kernel(const float* __restrict__ L,
                        const float* __restrict__ R,
                        float* __restrict__ out)
{
    __shared__ float r_s[CH][RW];        // 19 KB, r only; l stays in global/regs

    const int t  = threadIdx.x;          // 0..255
    const int w0 = blockIdx.x * WT;      // 0 or 256
    const int h  = blockIdx.y;
    const int n  = blockIdx.z;

    const size_t chw  = (size_t)HH * WW;                       // channel stride
    const size_t rowB = (size_t)n * CC * chw + (size_t)h * WW; // (n, c=0, h, 0)

    const int wg = t & 63;               // dg wave-uniform
    const int dg = t >> 6;               // 0..3
    const int wb = wg * WTILE;           // 0..252, multiple of 4
    const int d0 = dg * DTILE;           // 0,12,24,36
    // r_s col for (local w, d) is lw + 48 - d; needed [wb+37-d0, wb+51-d0];
    // aligned 16-float superset starts at:
    const int jA = wb + 36 - d0;         // multiple of 4; 0..288, +15 <= 303

    float acc[DTILE][WTILE];
    #pragma unroll
    for (int k = 0; k < DTILE; ++k)
        #pragma unroll
        for (int i = 0; i < WTILE; ++i)
            acc[k][i] = 0.f;

    // L prefetch chain (2-deep), runs straight through both halves
    const float* lp = L + rowB + w0 + wb;     // + c*chw per channel, aligned
    float4 lv0 = *(const float4*)(lp);
    float4 lv1 = *(const float4*)(lp + chw);

    for (int half = 0; half < 2; ++half) {
        const int c0 = half * CH;
        if (half) __syncthreads();       // drain half-0 compute before restage

        // ---- stage r: 16 rows x 76 float4 = 1216 slots, ~4.75/thread, coalesced
        #pragma unroll
        for (int k = 0; k < 5; ++k) {
            int idx = t + 256 * k;       // 0..1279
            if (idx < CH * 76) {
                int c   = idx / 76;      // 76 float4 per row
                int j4  = idx - c * 76;
                int g   = w0 - MAXD + 4 * j4;    // global w of this float4
                float4 v = make_float4(0.f, 0.f, 0.f, 0.f);
                if (g >= 0)              // w<0 -> zeros (zero pad / w<d)
                    v = *(const float4*)(R + rowB + (size_t)(c0 + c) * chw + g);
                *(float4*)&r_s[c][4 * j4] = v;
            }
        }
        __syncthreads();

        for (int cc = 0; cc < CH; ++cc) {
            const int c = c0 + cc;
            float4 lnext;
            if (c + 2 < CC)                       // uniform branch
                lnext = *(const float4*)(lp + (size_t)(c + 2) * chw);
            float rv[16];
            #pragma unroll
            for (int q = 0; q < 4; ++q)
                *(float4*)&rv[4 * q] = *(const float4*)&r_s[cc][jA + 4 * q];
            const float lf[4] = {lv0.x, lv0.y, lv0.z, lv0.w};
            #pragma unroll
            for (int k = 0; k < DTILE; ++k)
                #pragma unroll
                for (int i = 0; i < WTILE; ++i)
                    acc[k][i] += lf[i] * rv[12 + i - k];   // offsets 1..15, compile-time
            lv0 = lv1;
            lv1 = lnext;
        }
    }

    const float inv = 1.0f / 32.0f;      // mean over C, exact pow2
    #pragma unroll
    for (int k = 0; k < DTILE; ++k) {
        const int d = d0 + k;
        float4 o = make_float4(acc[k][0] * inv, acc[k][1] * inv,
                               acc[k][2] * inv, acc[k][3] * inv);
        *(float4*)(out + (((size_t)n * MAXD + d) * HH + h) * WW + w0 + wb) = o;
    }
}

extern "C" void kernel_launch(void* const* d_in, const int* in_sizes, int n_in,
                              void* d_out, int out_size, void* d_ws, size_t ws_size,
                              hipStream_t stream) {
    const float* L = (const float*)d_in[0];
    const float* R = (const float*)d_in[1];
    float* out = (float*)d_out;
    // d_in[2] (use_naive) is ignored per reference.
    dim3 grid(WW / WT, HH, NN);          // 2 x 256 x 4 = 2048 blocks
    cost_volume_kernel<<<grid, dim3(256, 1, 1), 0, stream>>>(L, R, out);
}

// Round 5
// 230.246 us; speedup vs baseline: 2.7581x; 1.9634x over previous
//
#include <hip/hip_runtime.h>

// Problem constants (fixed by reference)
#define CC 32
#define HH 256
#define WW 512
#define NN 4
#define MAXD 48

// Tiling: 256-wide w chunk, r-only LDS (full 32 channels, single stage,
// single barrier — round-0 proven). 384-thread blocks (6 waves) =
// 64 w-groups x 6 d-groups; per-thread 4w x 8d register tile.
//
// Register model (corrected in round 4): rocprof VGPR_Count is granules of 2.
// Round-0's 12d x 4w tile = ~115-128 TRUE VGPRs -> 4 waves/SIMD cap = 16
// waves/CU; that (not LDS) was the occupancy binder. Forcing 64 under that
// pressure spilled ~600 MB scratch (rounds 3/4). This version shrinks the
// tile: acc 32 + rv 12 + lv 12 + temps ~= 70 true VGPRs, budget 85 via
// __launch_bounds__(384,6) -> no spill, 6+ waves/SIMD.
// LDS 32*304*4 = 38912 B -> 4 blocks/CU x 6 waves = 24 waves/CU (75%).
#define WT 256
#define RW (WT + MAXD)    // 304 r columns staged (w0-48 .. w0+255)
#define DTILE 8           // d per thread; d0 = 8*dg (mult of 4 -> aligned window)
#define WTILE 4           // w per thread; wb mult of 4 -> aligned float4
#define NT 384            // 64 wg x 6 dg; dg = t>>6 wave-uniform

__global__ __launch_bounds__(NT, 6)
void cost_volume_kernel(const float* __restrict__ L,
                        const float* __restrict__ R,
                        float* __restrict__ out)
{
    __shared__ float r_s[CC][RW];        // 38 KB, r only; l stays in global/regs

    const int t  = threadIdx.x;          // 0..383
    const int w0 = blockIdx.x * WT;      // 0 or 256
    const int h  = blockIdx.y;
    const int n  = blockIdx.z;

    const size_t chw  = (size_t)HH * WW;                       // channel stride
    const size_t rowB = (size_t)n * CC * chw + (size_t)h * WW; // (n, c=0, h, 0)

    // ---- stage r: 32 rows x 76 float4 = 2432 slots, ~6.3/thread, coalesced
    #pragma unroll
    for (int k = 0; k < 7; ++k) {
        int idx = t + NT * k;            // 0..2687
        if (idx < 2432) {
            int c   = idx / 76;          // 76 float4 per row
            int j4  = idx - c * 76;
            int g   = w0 - MAXD + 4 * j4;    // global w of this float4
            float4 v = make_float4(0.f, 0.f, 0.f, 0.f);
            if (g >= 0)                  // w<0 -> zeros (zero pad / w<d)
                v = *(const float4*)(R + rowB + (size_t)c * chw + g);
            *(float4*)&r_s[c][4 * j4] = v;
        }
    }
    __syncthreads();                     // single barrier per block

    const int wg = t & 63;               // dg wave-uniform
    const int dg = t >> 6;               // 0..5
    const int wb = wg * WTILE;           // 0..252, multiple of 4
    const int d0 = dg * DTILE;           // 0,8,16,24,32,40
    // r_s col for (local w=wb+i, d=d0+k) is wb+i+48-d0-k, i in [0,3], k in [0,7]
    // -> window [wb+41-d0, wb+51-d0]; aligned 12-float superset starts at:
    const int jA = wb + 40 - d0;         // multiple of 4; 0..292, +11 <= 303

    float acc[DTILE][WTILE];
    #pragma unroll
    for (int k = 0; k < DTILE; ++k)
        #pragma unroll
        for (int i = 0; i < WTILE; ++i)
            acc[k][i] = 0.f;

    const float* lp = L + rowB + w0 + wb;     // + c*chw per channel, aligned
    float4 lv0 = *(const float4*)(lp);        // 2-deep prefetch
    float4 lv1 = *(const float4*)(lp + chw);
    for (int c = 0; c < CC; ++c) {
        float4 lnext;
        if (c + 2 < CC)                       // uniform branch
            lnext = *(const float4*)(lp + (size_t)(c + 2) * chw);
        float rv[12];
        #pragma unroll
        for (int q = 0; q < 3; ++q)
            *(float4*)&rv[4 * q] = *(const float4*)&r_s[c][jA + 4 * q];
        #pragma unroll
        for (int k = 0; k < DTILE; ++k) {
            acc[k][0] += lv0.x * rv[8 - k];   // offsets 1..11, compile-time
            acc[k][1] += lv0.y * rv[9 - k];
            acc[k][2] += lv0.z * rv[10 - k];
            acc[k][3] += lv0.w * rv[11 - k];
        }
        lv0 = lv1;
        lv1 = lnext;
    }

    const float inv = 1.0f / 32.0f;      // mean over C, exact pow2
    #pragma unroll
    for (int k = 0; k < DTILE; ++k) {
        const int d = d0 + k;
        float4 o = make_float4(acc[k][0] * inv, acc[k][1] * inv,
                               acc[k][2] * inv, acc[k][3] * inv);
        *(float4*)(out + (((size_t)n * MAXD + d) * HH + h) * WW + w0 + wb) = o;
    }
}

extern "C" void kernel_launch(void* const* d_in, const int* in_sizes, int n_in,
                              void* d_out, int out_size, void* d_ws, size_t ws_size,
                              hipStream_t stream) {
    const float* L = (const float*)d_in[0];
    const float* R = (const float*)d_in[1];
    float* out = (float*)d_out;
    // d_in[2] (use_naive) is ignored per reference.
    dim3 grid(WW / WT, HH, NN);          // 2 x 256 x 4 = 2048 blocks
    cost_volume_kernel<<<grid, dim3(NT, 1, 1), 0, stream>>>(L, R, out);
}